// Round 4
// baseline (259.516 us; speedup 1.0000x reference)
//
#include <hip/hip_runtime.h>

// UniformBottomUpHTMM: T=64 trees, depth 10 (N1=2047, heap layout), C=16,
// M=64, G=16. Single kernel, one block per (tree,g). All global loads are
// issued up-front as INDEPENDENT loads (inv_map + speculative x + params);
// the x[inv_map[.]] gather only happens on the (never-taken for identity
// inv_map) mismatch path, collapsing the dependent-miss chain to one epoch.
// Whole bottom-up pass runs in LDS; only the (64,16) ll sums leave the chip.

#define C_DIM 16
#define M_DIM 64
#define G_DIM 16
#define T_TREES 64
#define N1 2047

__global__ __launch_bounds__(256, 4) void htmm_kernel(
    const int* __restrict__ x,
    const int* __restrict__ inv_map,
    const float* __restrict__ lA,
    const float* __restrict__ lB,
    const float* __restrict__ lPi,
    float* __restrict__ out)
{
    const int g   = blockIdx.x & (G_DIM - 1);
    const int t   = blockIdx.x >> 4;
    const int tid = threadIdx.x;

    __shared__ __align__(16) float sA[C_DIM * C_DIM];   // sA[i*16+j]
    __shared__ __align__(16) float sB[C_DIM * M_DIM];   // sB[c*64+m]
    __shared__ __align__(16) float sPi[C_DIM];
    __shared__ __align__(16) unsigned char xs[2048];
    __shared__ float buf0[C_DIM * 256];   // L8 betas (SoA stride 256)
    __shared__ float buf1[C_DIM * 128];
    __shared__ float wsum[4];

    const int base = t * N1;

    // ---- Phase 0: issue ALL independent global loads up front ----
    int iv[8], sx[8];
    #pragma unroll
    for (int k = 0; k < 8; ++k) {
        int i = tid + 256 * k;
        if (i < N1) {
            iv[k] = inv_map[base + i];   // coalesced
            sx[k] = x[base + i];         // coalesced, speculative (identity guess)
        } else { iv[k] = -1; sx[k] = 0; }
    }

    // param loads (independent of the above)
    const int jA = tid >> 4, iA = tid & 15;
    float vA = lA[(iA * C_DIM + jA) * G_DIM + g];
    const int cB = tid >> 4, lB16 = tid & 15;
    float e0 = lB[(cB * M_DIM + lB16 +  0) * G_DIM + g];
    float e1 = lB[(cB * M_DIM + lB16 + 16) * G_DIM + g];
    float e2 = lB[(cB * M_DIM + lB16 + 32) * G_DIM + g];
    float e3 = lB[(cB * M_DIM + lB16 + 48) * G_DIM + g];
    float vPi = (tid < C_DIM) ? lPi[tid * G_DIM + g] : 0.f;

    // ---- softmaxes (width-16 shuffle reductions) ----
    {   // A: softmax over i within each column jA
        float mx = vA;
        #pragma unroll
        for (int m = 1; m < 16; m <<= 1) mx = fmaxf(mx, __shfl_xor(mx, m, 16));
        float e = __expf(vA - mx);
        float s = e;
        #pragma unroll
        for (int m = 1; m < 16; m <<= 1) s += __shfl_xor(s, m, 16);
        sA[iA * C_DIM + jA] = e / s;
    }
    {   // B: softmax over m within row cB
        float mx = fmaxf(fmaxf(e0, e1), fmaxf(e2, e3));
        #pragma unroll
        for (int m = 1; m < 16; m <<= 1) mx = fmaxf(mx, __shfl_xor(mx, m, 16));
        e0 = __expf(e0 - mx); e1 = __expf(e1 - mx);
        e2 = __expf(e2 - mx); e3 = __expf(e3 - mx);
        float s = e0 + e1 + e2 + e3;
        #pragma unroll
        for (int m = 1; m < 16; m <<= 1) s += __shfl_xor(s, m, 16);
        float inv = 1.f / s;
        sB[cB * M_DIM + lB16 +  0] = e0 * inv;
        sB[cB * M_DIM + lB16 + 16] = e1 * inv;
        sB[cB * M_DIM + lB16 + 32] = e2 * inv;
        sB[cB * M_DIM + lB16 + 48] = e3 * inv;
    }
    if (tid < C_DIM) {  // Pi
        float mx = vPi;
        #pragma unroll
        for (int m = 1; m < 16; m <<= 1) mx = fmaxf(mx, __shfl_xor(mx, m, 16));
        float e = __expf(vPi - mx);
        float s = e;
        #pragma unroll
        for (int m = 1; m < 16; m <<= 1) s += __shfl_xor(s, m, 16);
        sPi[tid] = e / s;
    }

    // ---- resolve xs: use speculative value unless inv_map isn't identity ----
    #pragma unroll
    for (int k = 0; k < 8; ++k) {
        int i = tid + 256 * k;
        if (i < N1) {
            int v = sx[k];
            if (iv[k] != base + i) v = x[iv[k]];   // execz-skipped for identity
            xs[i] = (unsigned char)v;
        }
    }
    __syncthreads();

    float ll = 0.f;

    // ---- fused leaves (L10) + L9 + L8: one L8 node per thread ----
    {
        const int idx = tid;
        const int p8  = 255 + idx;
        float s8[C_DIM];
        #pragma unroll
        for (int k = 0; k < C_DIM; ++k) s8[k] = 0.f;
        #pragma unroll
        for (int c9 = 0; c9 < 2; ++c9) {
            const int p9 = 2 * p8 + 1 + c9;
            float s9[C_DIM];
            #pragma unroll
            for (int k = 0; k < C_DIM; ++k) s9[k] = 0.f;
            #pragma unroll
            for (int cl = 0; cl < 2; ++cl) {
                const int xv = xs[2 * p9 + 1 + cl];
                float b[C_DIM]; float nu = 0.f;
                #pragma unroll
                for (int k = 0; k < C_DIM; ++k) {
                    b[k] = sPi[k] * sB[k * M_DIM + xv];
                    nu += b[k];
                }
                float inv = 0.5f / nu;
                #pragma unroll
                for (int k = 0; k < C_DIM; ++k) s9[k] += b[k] * inv;
                ll += __logf(nu);
            }
            const int xv = xs[p9];
            float bp[C_DIM]; float nu = 0.f;
            #pragma unroll
            for (int i = 0; i < C_DIM; ++i) {
                float ti = 0.f;
                #pragma unroll
                for (int j4 = 0; j4 < 4; ++j4) {
                    float4 a = ((const float4*)(sA + i * C_DIM))[j4];
                    ti += a.x * s9[4*j4] + a.y * s9[4*j4+1]
                        + a.z * s9[4*j4+2] + a.w * s9[4*j4+3];
                }
                bp[i] = ti * sB[i * M_DIM + xv];
                nu += bp[i];
            }
            ll += __logf(nu);
            float inv = 0.5f / nu;
            #pragma unroll
            for (int k = 0; k < C_DIM; ++k) s8[k] += bp[k] * inv;
        }
        const int xv = xs[p8];
        float bp[C_DIM]; float nu = 0.f;
        #pragma unroll
        for (int i = 0; i < C_DIM; ++i) {
            float ti = 0.f;
            #pragma unroll
            for (int j4 = 0; j4 < 4; ++j4) {
                float4 a = ((const float4*)(sA + i * C_DIM))[j4];
                ti += a.x * s8[4*j4] + a.y * s8[4*j4+1]
                    + a.z * s8[4*j4+2] + a.w * s8[4*j4+3];
            }
            bp[i] = ti * sB[i * M_DIM + xv];
            nu += bp[i];
        }
        ll += __logf(nu);
        float inv = 1.f / nu;
        #pragma unroll
        for (int k = 0; k < C_DIM; ++k) buf0[k * 256 + idx] = bp[k] * inv;
    }
    __syncthreads();

    // ---- L7: 128 nodes ----
    if (tid < 128) {
        const int idx = tid;
        float s[C_DIM];
        #pragma unroll
        for (int j = 0; j < C_DIM; ++j) {
            float2 cv = ((const float2*)(buf0 + j * 256))[idx];
            s[j] = 0.5f * (cv.x + cv.y);
        }
        const int xv = xs[127 + idx];
        float bp[C_DIM]; float nu = 0.f;
        #pragma unroll
        for (int i = 0; i < C_DIM; ++i) {
            float ti = 0.f;
            #pragma unroll
            for (int j4 = 0; j4 < 4; ++j4) {
                float4 a = ((const float4*)(sA + i * C_DIM))[j4];
                ti += a.x * s[4*j4] + a.y * s[4*j4+1]
                    + a.z * s[4*j4+2] + a.w * s[4*j4+3];
            }
            bp[i] = ti * sB[i * M_DIM + xv];
            nu += bp[i];
        }
        ll += __logf(nu);
        float inv = 1.f / nu;
        #pragma unroll
        for (int i = 0; i < C_DIM; ++i) buf1[i * 128 + idx] = bp[i] * inv;
    }
    __syncthreads();

    // ---- L6..L0 (64..1 nodes): wave 0 only, LDS fences instead of barriers
    if (tid < 64) {
        float* cur = buf1; int cs = 128;
        float* nxt = buf0; int ns = 256;
        for (int cnt = 64; cnt >= 1; cnt >>= 1) {
            if (tid < cnt) {
                const int idx = tid;
                float s[C_DIM];
                #pragma unroll
                for (int j = 0; j < C_DIM; ++j) {
                    float a  = cur[j * cs + 2 * idx];
                    float b2 = cur[j * cs + 2 * idx + 1];
                    s[j] = 0.5f * (a + b2);
                }
                const int xv = xs[cnt - 1 + idx];
                float bp[C_DIM]; float nu = 0.f;
                #pragma unroll
                for (int i = 0; i < C_DIM; ++i) {
                    float ti = 0.f;
                    #pragma unroll
                    for (int j4 = 0; j4 < 4; ++j4) {
                        float4 a = ((const float4*)(sA + i * C_DIM))[j4];
                        ti += a.x * s[4*j4] + a.y * s[4*j4+1]
                            + a.z * s[4*j4+2] + a.w * s[4*j4+3];
                    }
                    bp[i] = ti * sB[i * M_DIM + xv];
                    nu += bp[i];
                }
                ll += __logf(nu);
                float inv = 1.f / nu;
                #pragma unroll
                for (int i = 0; i < C_DIM; ++i) nxt[i * ns + idx] = bp[i] * inv;
            }
            asm volatile("s_waitcnt lgkmcnt(0)" ::: "memory");
            __builtin_amdgcn_wave_barrier();
            float* tp = cur; cur = nxt; nxt = tp;
            int ts = cs; cs = ns; ns = ts;
        }
    }

    // ---- reduce ll across block ----
    float v = ll;
    #pragma unroll
    for (int off = 32; off > 0; off >>= 1) v += __shfl_down(v, off, 64);
    if ((tid & 63) == 0) wsum[tid >> 6] = v;
    __syncthreads();
    if (tid == 0) out[t * G_DIM + g] = wsum[0] + wsum[1] + wsum[2] + wsum[3];
}

extern "C" void kernel_launch(void* const* d_in, const int* in_sizes, int n_in,
                              void* d_out, int out_size, void* d_ws, size_t ws_size,
                              hipStream_t stream) {
    const int*   x       = (const int*)d_in[0];
    const int*   inv_map = (const int*)d_in[6];
    const float* lA      = (const float*)d_in[7];
    const float* lB      = (const float*)d_in[8];
    const float* lPi     = (const float*)d_in[9];
    float* out = (float*)d_out;

    htmm_kernel<<<dim3(T_TREES * G_DIM), dim3(256), 0, stream>>>(
        x, inv_map, lA, lB, lPi, out);
}

// Round 5
// 235.853 us; speedup vs baseline: 1.1003x; 1.1003x over previous
//
#include <hip/hip_runtime.h>

// UniformBottomUpHTMM: T=64 trees, depth 10 (N1=2047, heap layout), C=16,
// M=64, G=16. Two-phase (r2 structure, best measured):
//   prep_kernel: softmax(A,B,Pi) per g -> compact blobs in d_ws, and
//                xs[t][i] = uint8(x[inv_map[t*2047+i]]) padded to 2048/tree.
//   htmm_kernel: one block per (t,g); ~7.3KB compact coalesced reads, then
//                the whole bottom-up pass runs in LDS.
// Block swizzle: bid = g*64+t so all 16 g-blocks of a tree share an XCD
// (bid % 8 == t % 8) -> each xs blob fetched from HBM once.

#define C_DIM 16
#define M_DIM 64
#define G_DIM 16
#define T_TREES 64
#define N1 2047

#define PAR_STRIDE 1536
#define XS_BYTE_OFF (G_DIM * PAR_STRIDE * 4)

__global__ __launch_bounds__(256) void prep_kernel(
    const int* __restrict__ x,
    const int* __restrict__ inv_map,
    const float* __restrict__ lA,
    const float* __restrict__ lB,
    const float* __restrict__ lPi,
    float* __restrict__ ws)
{
    const int tid = threadIdx.x;
    const int bid = blockIdx.x;

    // ---- xs gather: 512 blocks cover 64 trees * 2048 slots ----
    {
        int slot = bid * 256 + tid;            // [0, 131072)
        int t = slot >> 11, i = slot & 2047;
        unsigned char v = 0;
        if (i < N1) v = (unsigned char)x[inv_map[t * N1 + i]];
        ((unsigned char*)ws)[XS_BYTE_OFF + slot] = v;
    }

    // ---- params: first 16 blocks, one g each ----
    if (bid < G_DIM) {
        const int g = bid;
        float* pg = ws + g * PAR_STRIDE;
        {   // A: softmax over i within 16-lane segments
            int j = tid >> 4, i = tid & 15;
            float v = lA[(i * C_DIM + j) * G_DIM + g];
            float mx = v;
            #pragma unroll
            for (int m = 1; m < 16; m <<= 1) mx = fmaxf(mx, __shfl_xor(mx, m, 16));
            float e = __expf(v - mx);
            float s = e;
            #pragma unroll
            for (int m = 1; m < 16; m <<= 1) s += __shfl_xor(s, m, 16);
            pg[i * C_DIM + j] = e / s;
        }
        {   // B: softmax over m, row c, 4 symbols per lane
            int c = tid >> 4, l16 = tid & 15;
            float e0 = lB[(c * M_DIM + l16 +  0) * G_DIM + g];
            float e1 = lB[(c * M_DIM + l16 + 16) * G_DIM + g];
            float e2 = lB[(c * M_DIM + l16 + 32) * G_DIM + g];
            float e3 = lB[(c * M_DIM + l16 + 48) * G_DIM + g];
            float mx = fmaxf(fmaxf(e0, e1), fmaxf(e2, e3));
            #pragma unroll
            for (int m = 1; m < 16; m <<= 1) mx = fmaxf(mx, __shfl_xor(mx, m, 16));
            e0 = __expf(e0 - mx); e1 = __expf(e1 - mx);
            e2 = __expf(e2 - mx); e3 = __expf(e3 - mx);
            float s = e0 + e1 + e2 + e3;
            #pragma unroll
            for (int m = 1; m < 16; m <<= 1) s += __shfl_xor(s, m, 16);
            float inv = 1.f / s;
            pg[256 + c * M_DIM + l16 +  0] = e0 * inv;
            pg[256 + c * M_DIM + l16 + 16] = e1 * inv;
            pg[256 + c * M_DIM + l16 + 32] = e2 * inv;
            pg[256 + c * M_DIM + l16 + 48] = e3 * inv;
        }
        if (tid < C_DIM) {  // Pi
            float v = lPi[tid * G_DIM + g];
            float mx = v;
            #pragma unroll
            for (int m = 1; m < 16; m <<= 1) mx = fmaxf(mx, __shfl_xor(mx, m, 16));
            float e = __expf(v - mx);
            float s = e;
            #pragma unroll
            for (int m = 1; m < 16; m <<= 1) s += __shfl_xor(s, m, 16);
            pg[1280 + tid] = e / s;
        }
    }
}

__global__ __launch_bounds__(256, 4) void htmm_kernel(
    const float* __restrict__ ws,
    float* __restrict__ out)
{
    // swizzled: same-tree blocks share an XCD (bid % 8 == t % 8)
    const int g   = blockIdx.x >> 6;
    const int t   = blockIdx.x & (T_TREES - 1);
    const int tid = threadIdx.x;

    __shared__ __align__(16) float sA[C_DIM * C_DIM];
    __shared__ __align__(16) float sB[C_DIM * M_DIM];
    __shared__ __align__(16) float sPi[C_DIM];
    __shared__ __align__(16) unsigned char xs[2048];
    __shared__ float buf0[C_DIM * 256];   // L8 betas (SoA stride 256)
    __shared__ float buf1[C_DIM * 128];
    __shared__ float wsum[4];

    // ---- compact, coalesced prologue loads (all independent) ----
    {
        const float* pg = ws + g * PAR_STRIDE;
        ((float4*)sB)[tid] = ((const float4*)(pg + 256))[tid];
        if (tid < 64)  ((float4*)sA)[tid]  = ((const float4*)pg)[tid];
        if (tid < 4)   ((float4*)sPi)[tid] = ((const float4*)(pg + 1280))[tid];
        if (tid < 128) ((int4*)xs)[tid] =
            ((const int4*)((const unsigned char*)ws + XS_BYTE_OFF + t * 2048))[tid];
    }
    __syncthreads();

    float ll = 0.f;

    // ---- fused leaves (L10) + L9 + L8: one L8 node per thread ----
    {
        const int idx = tid;
        const int p8  = 255 + idx;
        float s8[C_DIM];
        #pragma unroll
        for (int k = 0; k < C_DIM; ++k) s8[k] = 0.f;
        #pragma unroll
        for (int c9 = 0; c9 < 2; ++c9) {
            const int p9 = 2 * p8 + 1 + c9;
            float s9[C_DIM];
            #pragma unroll
            for (int k = 0; k < C_DIM; ++k) s9[k] = 0.f;
            #pragma unroll
            for (int cl = 0; cl < 2; ++cl) {
                const int xv = xs[2 * p9 + 1 + cl];
                float b[C_DIM]; float nu = 0.f;
                #pragma unroll
                for (int k = 0; k < C_DIM; ++k) {
                    b[k] = sPi[k] * sB[k * M_DIM + xv];
                    nu += b[k];
                }
                float inv = 0.5f / nu;
                #pragma unroll
                for (int k = 0; k < C_DIM; ++k) s9[k] += b[k] * inv;
                ll += __logf(nu);
            }
            const int xv = xs[p9];
            float bp[C_DIM]; float nu = 0.f;
            #pragma unroll
            for (int i = 0; i < C_DIM; ++i) {
                float ti = 0.f;
                #pragma unroll
                for (int j = 0; j < C_DIM; ++j) ti += sA[i * C_DIM + j] * s9[j];
                bp[i] = ti * sB[i * M_DIM + xv];
                nu += bp[i];
            }
            ll += __logf(nu);
            float inv = 0.5f / nu;
            #pragma unroll
            for (int k = 0; k < C_DIM; ++k) s8[k] += bp[k] * inv;
        }
        const int xv = xs[p8];
        float bp[C_DIM]; float nu = 0.f;
        #pragma unroll
        for (int i = 0; i < C_DIM; ++i) {
            float ti = 0.f;
            #pragma unroll
            for (int j = 0; j < C_DIM; ++j) ti += sA[i * C_DIM + j] * s8[j];
            bp[i] = ti * sB[i * M_DIM + xv];
            nu += bp[i];
        }
        ll += __logf(nu);
        float inv = 1.f / nu;
        #pragma unroll
        for (int k = 0; k < C_DIM; ++k) buf0[k * 256 + idx] = bp[k] * inv;
    }
    __syncthreads();

    // ---- L7: 128 nodes ----
    if (tid < 128) {
        const int idx = tid;
        float s[C_DIM];
        #pragma unroll
        for (int j = 0; j < C_DIM; ++j) {
            float2 cv = ((const float2*)(buf0 + j * 256))[idx];
            s[j] = 0.5f * (cv.x + cv.y);
        }
        const int xv = xs[127 + idx];
        float bp[C_DIM]; float nu = 0.f;
        #pragma unroll
        for (int i = 0; i < C_DIM; ++i) {
            float ti = 0.f;
            #pragma unroll
            for (int j = 0; j < C_DIM; ++j) ti += sA[i * C_DIM + j] * s[j];
            bp[i] = ti * sB[i * M_DIM + xv];
            nu += bp[i];
        }
        ll += __logf(nu);
        float inv = 1.f / nu;
        #pragma unroll
        for (int i = 0; i < C_DIM; ++i) buf1[i * 128 + idx] = bp[i] * inv;
    }
    __syncthreads();

    // ---- L6..L0 (64..1 nodes): wave 0 only, LDS fences not barriers ----
    if (tid < 64) {
        float* cur = buf1; int cs = 128;
        float* nxt = buf0; int ns = 256;
        for (int cnt = 64; cnt >= 1; cnt >>= 1) {
            if (tid < cnt) {
                const int idx = tid;
                float s[C_DIM];
                #pragma unroll
                for (int j = 0; j < C_DIM; ++j) {
                    float a  = cur[j * cs + 2 * idx];
                    float b2 = cur[j * cs + 2 * idx + 1];
                    s[j] = 0.5f * (a + b2);
                }
                const int xv = xs[cnt - 1 + idx];
                float bp[C_DIM]; float nu = 0.f;
                #pragma unroll
                for (int i = 0; i < C_DIM; ++i) {
                    float ti = 0.f;
                    #pragma unroll
                    for (int j = 0; j < C_DIM; ++j) ti += sA[i * C_DIM + j] * s[j];
                    bp[i] = ti * sB[i * M_DIM + xv];
                    nu += bp[i];
                }
                ll += __logf(nu);
                float inv = 1.f / nu;
                #pragma unroll
                for (int i = 0; i < C_DIM; ++i) nxt[i * ns + idx] = bp[i] * inv;
            }
            asm volatile("s_waitcnt lgkmcnt(0)" ::: "memory");
            __builtin_amdgcn_wave_barrier();
            float* tp = cur; cur = nxt; nxt = tp;
            int ts = cs; cs = ns; ns = ts;
        }
    }

    // ---- reduce ll across block ----
    float v = ll;
    #pragma unroll
    for (int off = 32; off > 0; off >>= 1) v += __shfl_down(v, off, 64);
    if ((tid & 63) == 0) wsum[tid >> 6] = v;
    __syncthreads();
    if (tid == 0) out[t * G_DIM + g] = wsum[0] + wsum[1] + wsum[2] + wsum[3];
}

extern "C" void kernel_launch(void* const* d_in, const int* in_sizes, int n_in,
                              void* d_out, int out_size, void* d_ws, size_t ws_size,
                              hipStream_t stream) {
    const int*   x       = (const int*)d_in[0];
    const int*   inv_map = (const int*)d_in[6];
    const float* lA      = (const float*)d_in[7];
    const float* lB      = (const float*)d_in[8];
    const float* lPi     = (const float*)d_in[9];
    float* ws  = (float*)d_ws;
    float* out = (float*)d_out;

    prep_kernel<<<dim3(512), dim3(256), 0, stream>>>(x, inv_map, lA, lB, lPi, ws);
    htmm_kernel<<<dim3(T_TREES * G_DIM), dim3(256), 0, stream>>>(ws, out);
}

// Round 7
// 233.826 us; speedup vs baseline: 1.1099x; 1.0087x over previous
//
#include <hip/hip_runtime.h>

// UniformBottomUpHTMM: T=64 trees, depth 10 (N1=2047, heap layout), C=16,
// M=64, G=16. Two-phase (r5 structure, best measured at 235.9 us):
//   prep_kernel: softmax(A,B,Pi) per g -> compact blobs in d_ws, and
//                xs[t][i] = uint8(x[inv_map[t*2047+i]]) padded to 2048/tree.
//   htmm_kernel: one block per (t,g); ~7.3KB compact coalesced reads, then
//                the whole bottom-up pass runs in LDS.
// Block swizzle: bid = g*64+t so all 16 g-blocks of a tree share an XCD
// (bid % 8 == t % 8) -> each xs blob fetched from HBM once.
//
// Session finding (r1-r6): total time is floored at ~235 us by harness-side
// restore/poison traffic (~460 MB/iter visible in TCC counters) draining
// through HBM ahead of the dispatch; true kernel execution is ~18 us
// (VALUBusy ~10% of a drain-dominated window, kernel writes only 4 KB).
// Cooperative-launch window merging fails in this harness (r6).

#define C_DIM 16
#define M_DIM 64
#define G_DIM 16
#define T_TREES 64
#define N1 2047

#define PAR_STRIDE 1536
#define XS_BYTE_OFF (G_DIM * PAR_STRIDE * 4)

__global__ __launch_bounds__(256) void prep_kernel(
    const int* __restrict__ x,
    const int* __restrict__ inv_map,
    const float* __restrict__ lA,
    const float* __restrict__ lB,
    const float* __restrict__ lPi,
    float* __restrict__ ws)
{
    const int tid = threadIdx.x;
    const int bid = blockIdx.x;

    // ---- xs gather: 512 blocks cover 64 trees * 2048 slots ----
    {
        int slot = bid * 256 + tid;            // [0, 131072)
        int t = slot >> 11, i = slot & 2047;
        unsigned char v = 0;
        if (i < N1) v = (unsigned char)x[inv_map[t * N1 + i]];
        ((unsigned char*)ws)[XS_BYTE_OFF + slot] = v;
    }

    // ---- params: first 16 blocks, one g each ----
    if (bid < G_DIM) {
        const int g = bid;
        float* pg = ws + g * PAR_STRIDE;
        {   // A: softmax over i within 16-lane segments
            int j = tid >> 4, i = tid & 15;
            float v = lA[(i * C_DIM + j) * G_DIM + g];
            float mx = v;
            #pragma unroll
            for (int m = 1; m < 16; m <<= 1) mx = fmaxf(mx, __shfl_xor(mx, m, 16));
            float e = __expf(v - mx);
            float s = e;
            #pragma unroll
            for (int m = 1; m < 16; m <<= 1) s += __shfl_xor(s, m, 16);
            pg[i * C_DIM + j] = e / s;
        }
        {   // B: softmax over m, row c, 4 symbols per lane
            int c = tid >> 4, l16 = tid & 15;
            float e0 = lB[(c * M_DIM + l16 +  0) * G_DIM + g];
            float e1 = lB[(c * M_DIM + l16 + 16) * G_DIM + g];
            float e2 = lB[(c * M_DIM + l16 + 32) * G_DIM + g];
            float e3 = lB[(c * M_DIM + l16 + 48) * G_DIM + g];
            float mx = fmaxf(fmaxf(e0, e1), fmaxf(e2, e3));
            #pragma unroll
            for (int m = 1; m < 16; m <<= 1) mx = fmaxf(mx, __shfl_xor(mx, m, 16));
            e0 = __expf(e0 - mx); e1 = __expf(e1 - mx);
            e2 = __expf(e2 - mx); e3 = __expf(e3 - mx);
            float s = e0 + e1 + e2 + e3;
            #pragma unroll
            for (int m = 1; m < 16; m <<= 1) s += __shfl_xor(s, m, 16);
            float inv = 1.f / s;
            pg[256 + c * M_DIM + l16 +  0] = e0 * inv;
            pg[256 + c * M_DIM + l16 + 16] = e1 * inv;
            pg[256 + c * M_DIM + l16 + 32] = e2 * inv;
            pg[256 + c * M_DIM + l16 + 48] = e3 * inv;
        }
        if (tid < C_DIM) {  // Pi
            float v = lPi[tid * G_DIM + g];
            float mx = v;
            #pragma unroll
            for (int m = 1; m < 16; m <<= 1) mx = fmaxf(mx, __shfl_xor(mx, m, 16));
            float e = __expf(v - mx);
            float s = e;
            #pragma unroll
            for (int m = 1; m < 16; m <<= 1) s += __shfl_xor(s, m, 16);
            pg[1280 + tid] = e / s;
        }
    }
}

__global__ __launch_bounds__(256, 4) void htmm_kernel(
    const float* __restrict__ ws,
    float* __restrict__ out)
{
    // swizzled: same-tree blocks share an XCD (bid % 8 == t % 8)
    const int g   = blockIdx.x >> 6;
    const int t   = blockIdx.x & (T_TREES - 1);
    const int tid = threadIdx.x;

    __shared__ __align__(16) float sA[C_DIM * C_DIM];
    __shared__ __align__(16) float sB[C_DIM * M_DIM];
    __shared__ __align__(16) float sPi[C_DIM];
    __shared__ __align__(16) unsigned char xs[2048];
    __shared__ float buf0[C_DIM * 256];   // L8 betas (SoA stride 256)
    __shared__ float buf1[C_DIM * 128];
    __shared__ float wsum[4];

    // ---- compact, coalesced prologue loads (all independent) ----
    {
        const float* pg = ws + g * PAR_STRIDE;
        ((float4*)sB)[tid] = ((const float4*)(pg + 256))[tid];
        if (tid < 64)  ((float4*)sA)[tid]  = ((const float4*)pg)[tid];
        if (tid < 4)   ((float4*)sPi)[tid] = ((const float4*)(pg + 1280))[tid];
        if (tid < 128) ((int4*)xs)[tid] =
            ((const int4*)((const unsigned char*)ws + XS_BYTE_OFF + t * 2048))[tid];
    }
    __syncthreads();

    float ll = 0.f;

    // ---- fused leaves (L10) + L9 + L8: one L8 node per thread ----
    {
        const int idx = tid;
        const int p8  = 255 + idx;
        float s8[C_DIM];
        #pragma unroll
        for (int k = 0; k < C_DIM; ++k) s8[k] = 0.f;
        #pragma unroll
        for (int c9 = 0; c9 < 2; ++c9) {
            const int p9 = 2 * p8 + 1 + c9;
            float s9[C_DIM];
            #pragma unroll
            for (int k = 0; k < C_DIM; ++k) s9[k] = 0.f;
            #pragma unroll
            for (int cl = 0; cl < 2; ++cl) {
                const int xv = xs[2 * p9 + 1 + cl];
                float b[C_DIM]; float nu = 0.f;
                #pragma unroll
                for (int k = 0; k < C_DIM; ++k) {
                    b[k] = sPi[k] * sB[k * M_DIM + xv];
                    nu += b[k];
                }
                float inv = 0.5f / nu;
                #pragma unroll
                for (int k = 0; k < C_DIM; ++k) s9[k] += b[k] * inv;
                ll += __logf(nu);
            }
            const int xv = xs[p9];
            float bp[C_DIM]; float nu = 0.f;
            #pragma unroll
            for (int i = 0; i < C_DIM; ++i) {
                float ti = 0.f;
                #pragma unroll
                for (int j = 0; j < C_DIM; ++j) ti += sA[i * C_DIM + j] * s9[j];
                bp[i] = ti * sB[i * M_DIM + xv];
                nu += bp[i];
            }
            ll += __logf(nu);
            float inv = 0.5f / nu;
            #pragma unroll
            for (int k = 0; k < C_DIM; ++k) s8[k] += bp[k] * inv;
        }
        const int xv = xs[p8];
        float bp[C_DIM]; float nu = 0.f;
        #pragma unroll
        for (int i = 0; i < C_DIM; ++i) {
            float ti = 0.f;
            #pragma unroll
            for (int j = 0; j < C_DIM; ++j) ti += sA[i * C_DIM + j] * s8[j];
            bp[i] = ti * sB[i * M_DIM + xv];
            nu += bp[i];
        }
        ll += __logf(nu);
        float inv = 1.f / nu;
        #pragma unroll
        for (int k = 0; k < C_DIM; ++k) buf0[k * 256 + idx] = bp[k] * inv;
    }
    __syncthreads();

    // ---- L7: 128 nodes ----
    if (tid < 128) {
        const int idx = tid;
        float s[C_DIM];
        #pragma unroll
        for (int j = 0; j < C_DIM; ++j) {
            float2 cv = ((const float2*)(buf0 + j * 256))[idx];
            s[j] = 0.5f * (cv.x + cv.y);
        }
        const int xv = xs[127 + idx];
        float bp[C_DIM]; float nu = 0.f;
        #pragma unroll
        for (int i = 0; i < C_DIM; ++i) {
            float ti = 0.f;
            #pragma unroll
            for (int j = 0; j < C_DIM; ++j) ti += sA[i * C_DIM + j] * s[j];
            bp[i] = ti * sB[i * M_DIM + xv];
            nu += bp[i];
        }
        ll += __logf(nu);
        float inv = 1.f / nu;
        #pragma unroll
        for (int i = 0; i < C_DIM; ++i) buf1[i * 128 + idx] = bp[i] * inv;
    }
    __syncthreads();

    // ---- L6..L0 (64..1 nodes): wave 0 only, LDS fences not barriers ----
    if (tid < 64) {
        float* cur = buf1; int cs = 128;
        float* nxt = buf0; int ns = 256;
        for (int cnt = 64; cnt >= 1; cnt >>= 1) {
            if (tid < cnt) {
                const int idx = tid;
                float s[C_DIM];
                #pragma unroll
                for (int j = 0; j < C_DIM; ++j) {
                    float a  = cur[j * cs + 2 * idx];
                    float b2 = cur[j * cs + 2 * idx + 1];
                    s[j] = 0.5f * (a + b2);
                }
                const int xv = xs[cnt - 1 + idx];
                float bp[C_DIM]; float nu = 0.f;
                #pragma unroll
                for (int i = 0; i < C_DIM; ++i) {
                    float ti = 0.f;
                    #pragma unroll
                    for (int j = 0; j < C_DIM; ++j) ti += sA[i * C_DIM + j] * s[j];
                    bp[i] = ti * sB[i * M_DIM + xv];
                    nu += bp[i];
                }
                ll += __logf(nu);
                float inv = 1.f / nu;
                #pragma unroll
                for (int i = 0; i < C_DIM; ++i) nxt[i * ns + idx] = bp[i] * inv;
            }
            asm volatile("s_waitcnt lgkmcnt(0)" ::: "memory");
            __builtin_amdgcn_wave_barrier();
            float* tp = cur; cur = nxt; nxt = tp;
            int ts = cs; cs = ns; ns = ts;
        }
    }

    // ---- reduce ll across block ----
    float v = ll;
    #pragma unroll
    for (int off = 32; off > 0; off >>= 1) v += __shfl_down(v, off, 64);
    if ((tid & 63) == 0) wsum[tid >> 6] = v;
    __syncthreads();
    if (tid == 0) out[t * G_DIM + g] = wsum[0] + wsum[1] + wsum[2] + wsum[3];
}

extern "C" void kernel_launch(void* const* d_in, const int* in_sizes, int n_in,
                              void* d_out, int out_size, void* d_ws, size_t ws_size,
                              hipStream_t stream) {
    const int*   x       = (const int*)d_in[0];
    const int*   inv_map = (const int*)d_in[6];
    const float* lA      = (const float*)d_in[7];
    const float* lB      = (const float*)d_in[8];
    const float* lPi     = (const float*)d_in[9];
    float* ws  = (float*)d_ws;
    float* out = (float*)d_out;

    prep_kernel<<<dim3(512), dim3(256), 0, stream>>>(x, inv_map, lA, lB, lPi, ws);
    htmm_kernel<<<dim3(T_TREES * G_DIM), dim3(256), 0, stream>>>(ws, out);
}

// Round 8
// 206.061 us; speedup vs baseline: 1.2594x; 1.1347x over previous
//
#include <hip/hip_runtime.h>

// UniformBottomUpHTMM: T=64 trees, depth 10 (N1=2047, heap layout), C=16,
// M=64, G=16. SINGLE kernel, 512 blocks, hand-rolled device-scope barrier:
//   Phase A: xs[t][i] = uint8(x[inv_map[.]]) gather (coalesced across grid)
//            + per-g softmax(A,B,Pi) -> compact blobs in d_ws (blocks 0-15).
//   device barrier (atomic counter in d_ws; 0xAA-poison normalized via CAS;
//            512 blocks @ __launch_bounds__(256,2) are guaranteed co-resident:
//            31.5KB LDS -> 5/CU by LDS, 64 VGPR -> 8 waves/SIMD, grid = 2*256CU)
//   Phase B: block = (t, gh); bid%8 == t%8 keeps same-tree blocks on one XCD;
//            each block runs the full LDS bottom-up pass for g = gh and gh+8.
// Only the (64,16) ll sums leave the chip.
//
// Session model (r1-r7): total time floored by ~460 MB/iter harness
// restore/poison drain (TCC counters show WRITE=292MB in a window where the
// kernel writes 4KB); true kernel exec ~18 us. This merge removes the last
// serialized window/gap. Cooperative-launch API fails here (r6) - this uses
// a plain launch + atomic spin barrier instead.

#define C_DIM 16
#define M_DIM 64
#define G_DIM 16
#define T_TREES 64
#define N1 2047

#define PAR_STRIDE 1536
#define XS_BYTE_OFF (G_DIM * PAR_STRIDE * 4)     // 98304
#define BAR_BYTE_OFF (512 * 1024)                // counter cell, past used region
#define NBLOCKS 512u

__global__ __launch_bounds__(256, 2) void htmm_fused(
    const int* __restrict__ x,
    const int* __restrict__ inv_map,
    const float* __restrict__ lA,
    const float* __restrict__ lB,
    const float* __restrict__ lPi,
    float* __restrict__ ws,
    float* __restrict__ out)
{
    const int bid = blockIdx.x;      // 512 blocks
    const int tid = threadIdx.x;

    __shared__ __align__(16) float sA[C_DIM * C_DIM];
    __shared__ __align__(16) float sB[C_DIM * M_DIM];
    __shared__ __align__(16) float sPi[C_DIM];
    __shared__ __align__(16) unsigned char xs[2048];
    __shared__ float buf0[C_DIM * 256];   // L8 betas (SoA stride 256)
    __shared__ float buf1[C_DIM * 128];
    __shared__ float wsum[4];

    // ================= Phase A =================
    {   // xs gather: 512*256 = 131072 slots = 64 trees * 2048 (coalesced)
        int slot = bid * 256 + tid;
        int t = slot >> 11, i = slot & 2047;
        unsigned char v = 0;
        if (i < N1) v = (unsigned char)x[inv_map[t * N1 + i]];
        ((unsigned char*)ws)[XS_BYTE_OFF + slot] = v;
    }
    if (bid < G_DIM) {   // params: one g per block
        const int g = bid;
        float* pg = ws + g * PAR_STRIDE;
        {   // A: softmax over i within 16-lane segments
            int j = tid >> 4, i = tid & 15;
            float v = lA[(i * C_DIM + j) * G_DIM + g];
            float mx = v;
            #pragma unroll
            for (int m = 1; m < 16; m <<= 1) mx = fmaxf(mx, __shfl_xor(mx, m, 16));
            float e = __expf(v - mx);
            float s = e;
            #pragma unroll
            for (int m = 1; m < 16; m <<= 1) s += __shfl_xor(s, m, 16);
            pg[i * C_DIM + j] = e / s;
        }
        {   // B: softmax over m, row c, 4 symbols per lane
            int c = tid >> 4, l16 = tid & 15;
            float e0 = lB[(c * M_DIM + l16 +  0) * G_DIM + g];
            float e1 = lB[(c * M_DIM + l16 + 16) * G_DIM + g];
            float e2 = lB[(c * M_DIM + l16 + 32) * G_DIM + g];
            float e3 = lB[(c * M_DIM + l16 + 48) * G_DIM + g];
            float mx = fmaxf(fmaxf(e0, e1), fmaxf(e2, e3));
            #pragma unroll
            for (int m = 1; m < 16; m <<= 1) mx = fmaxf(mx, __shfl_xor(mx, m, 16));
            e0 = __expf(e0 - mx); e1 = __expf(e1 - mx);
            e2 = __expf(e2 - mx); e3 = __expf(e3 - mx);
            float s = e0 + e1 + e2 + e3;
            #pragma unroll
            for (int m = 1; m < 16; m <<= 1) s += __shfl_xor(s, m, 16);
            float inv = 1.f / s;
            pg[256 + c * M_DIM + l16 +  0] = e0 * inv;
            pg[256 + c * M_DIM + l16 + 16] = e1 * inv;
            pg[256 + c * M_DIM + l16 + 32] = e2 * inv;
            pg[256 + c * M_DIM + l16 + 48] = e3 * inv;
        }
        if (tid < C_DIM) {  // Pi
            float v = lPi[tid * G_DIM + g];
            float mx = v;
            #pragma unroll
            for (int m = 1; m < 16; m <<= 1) mx = fmaxf(mx, __shfl_xor(mx, m, 16));
            float e = __expf(v - mx);
            float s = e;
            #pragma unroll
            for (int m = 1; m < 16; m <<= 1) s += __shfl_xor(s, m, 16);
            pg[1280 + tid] = e / s;
        }
    }

    // ================= device barrier =================
    {
        __syncthreads();                       // all phase-A stores issued
        unsigned int* cnt = (unsigned int*)((char*)ws + BAR_BYTE_OFF);
        if (tid == 0) {
            __threadfence();                   // release phase-A writes (agent scope)
            atomicCAS(cnt, 0xAAAAAAAAu, 0u);   // normalize harness poison (once)
            atomicCAS(cnt, NBLOCKS, 0u);       // normalize stale counter (once)
            atomicAdd(cnt, 1u);
            while (__hip_atomic_load(cnt, __ATOMIC_RELAXED,
                                     __HIP_MEMORY_SCOPE_AGENT) < NBLOCKS)
                __builtin_amdgcn_s_sleep(8);
            __threadfence();                   // acquire other blocks' writes
        }
        __syncthreads();
    }

    // ================= Phase B =================
    const int gh = bid >> 6;          // 0..7 -> g = gh, gh+8
    const int t  = bid & (T_TREES-1); // bid%8 == t%8 -> same-tree blocks share XCD

    // tree symbols: load once (2KB, coalesced)
    if (tid < 128)
        ((int4*)xs)[tid] =
            ((const int4*)((const unsigned char*)ws + XS_BYTE_OFF + t * 2048))[tid];

    for (int rep = 0; rep < 2; ++rep) {
        const int g = gh + rep * 8;
        {   // compact param loads for this g
            const float* pg = ws + g * PAR_STRIDE;
            ((float4*)sB)[tid] = ((const float4*)(pg + 256))[tid];
            if (tid < 64)  ((float4*)sA)[tid]  = ((const float4*)pg)[tid];
            if (tid < 4)   ((float4*)sPi)[tid] = ((const float4*)(pg + 1280))[tid];
        }
        __syncthreads();

        float ll = 0.f;

        // ---- fused leaves (L10) + L9 + L8: one L8 node per thread ----
        {
            const int idx = tid;
            const int p8  = 255 + idx;
            float s8[C_DIM];
            #pragma unroll
            for (int k = 0; k < C_DIM; ++k) s8[k] = 0.f;
            #pragma unroll
            for (int c9 = 0; c9 < 2; ++c9) {
                const int p9 = 2 * p8 + 1 + c9;
                float s9[C_DIM];
                #pragma unroll
                for (int k = 0; k < C_DIM; ++k) s9[k] = 0.f;
                #pragma unroll
                for (int cl = 0; cl < 2; ++cl) {
                    const int xv = xs[2 * p9 + 1 + cl];
                    float b[C_DIM]; float nu = 0.f;
                    #pragma unroll
                    for (int k = 0; k < C_DIM; ++k) {
                        b[k] = sPi[k] * sB[k * M_DIM + xv];
                        nu += b[k];
                    }
                    float inv = 0.5f / nu;
                    #pragma unroll
                    for (int k = 0; k < C_DIM; ++k) s9[k] += b[k] * inv;
                    ll += __logf(nu);
                }
                const int xv = xs[p9];
                float bp[C_DIM]; float nu = 0.f;
                #pragma unroll
                for (int i = 0; i < C_DIM; ++i) {
                    float ti = 0.f;
                    #pragma unroll
                    for (int j = 0; j < C_DIM; ++j) ti += sA[i * C_DIM + j] * s9[j];
                    bp[i] = ti * sB[i * M_DIM + xv];
                    nu += bp[i];
                }
                ll += __logf(nu);
                float inv = 0.5f / nu;
                #pragma unroll
                for (int k = 0; k < C_DIM; ++k) s8[k] += bp[k] * inv;
            }
            const int xv = xs[p8];
            float bp[C_DIM]; float nu = 0.f;
            #pragma unroll
            for (int i = 0; i < C_DIM; ++i) {
                float ti = 0.f;
                #pragma unroll
                for (int j = 0; j < C_DIM; ++j) ti += sA[i * C_DIM + j] * s8[j];
                bp[i] = ti * sB[i * M_DIM + xv];
                nu += bp[i];
            }
            ll += __logf(nu);
            float inv = 1.f / nu;
            #pragma unroll
            for (int k = 0; k < C_DIM; ++k) buf0[k * 256 + idx] = bp[k] * inv;
        }
        __syncthreads();

        // ---- L7: 128 nodes ----
        if (tid < 128) {
            const int idx = tid;
            float s[C_DIM];
            #pragma unroll
            for (int j = 0; j < C_DIM; ++j) {
                float2 cv = ((const float2*)(buf0 + j * 256))[idx];
                s[j] = 0.5f * (cv.x + cv.y);
            }
            const int xv = xs[127 + idx];
            float bp[C_DIM]; float nu = 0.f;
            #pragma unroll
            for (int i = 0; i < C_DIM; ++i) {
                float ti = 0.f;
                #pragma unroll
                for (int j = 0; j < C_DIM; ++j) ti += sA[i * C_DIM + j] * s[j];
                bp[i] = ti * sB[i * M_DIM + xv];
                nu += bp[i];
            }
            ll += __logf(nu);
            float inv = 1.f / nu;
            #pragma unroll
            for (int i = 0; i < C_DIM; ++i) buf1[i * 128 + idx] = bp[i] * inv;
        }
        __syncthreads();

        // ---- L6..L0 (64..1 nodes): wave 0 only, LDS fences not barriers ----
        if (tid < 64) {
            float* cur = buf1; int cs = 128;
            float* nxt = buf0; int ns = 256;
            for (int cnt2 = 64; cnt2 >= 1; cnt2 >>= 1) {
                if (tid < cnt2) {
                    const int idx = tid;
                    float s[C_DIM];
                    #pragma unroll
                    for (int j = 0; j < C_DIM; ++j) {
                        float a  = cur[j * cs + 2 * idx];
                        float b2 = cur[j * cs + 2 * idx + 1];
                        s[j] = 0.5f * (a + b2);
                    }
                    const int xv = xs[cnt2 - 1 + idx];
                    float bp[C_DIM]; float nu = 0.f;
                    #pragma unroll
                    for (int i = 0; i < C_DIM; ++i) {
                        float ti = 0.f;
                        #pragma unroll
                        for (int j = 0; j < C_DIM; ++j) ti += sA[i * C_DIM + j] * s[j];
                        bp[i] = ti * sB[i * M_DIM + xv];
                        nu += bp[i];
                    }
                    ll += __logf(nu);
                    float inv = 1.f / nu;
                    #pragma unroll
                    for (int i = 0; i < C_DIM; ++i) nxt[i * ns + idx] = bp[i] * inv;
                }
                asm volatile("s_waitcnt lgkmcnt(0)" ::: "memory");
                __builtin_amdgcn_wave_barrier();
                float* tp = cur; cur = nxt; nxt = tp;
                int ts = cs; cs = ns; ns = ts;
            }
        }

        // ---- reduce ll across block ----
        float v = ll;
        #pragma unroll
        for (int off = 32; off > 0; off >>= 1) v += __shfl_down(v, off, 64);
        if ((tid & 63) == 0) wsum[tid >> 6] = v;
        __syncthreads();
        if (tid == 0) out[t * G_DIM + g] = wsum[0] + wsum[1] + wsum[2] + wsum[3];
        __syncthreads();   // buffers/params reused next rep
    }
}

extern "C" void kernel_launch(void* const* d_in, const int* in_sizes, int n_in,
                              void* d_out, int out_size, void* d_ws, size_t ws_size,
                              hipStream_t stream) {
    const int*   x       = (const int*)d_in[0];
    const int*   inv_map = (const int*)d_in[6];
    const float* lA      = (const float*)d_in[7];
    const float* lB      = (const float*)d_in[8];
    const float* lPi     = (const float*)d_in[9];
    float* ws  = (float*)d_ws;
    float* out = (float*)d_out;

    htmm_fused<<<dim3(NBLOCKS), dim3(256), 0, stream>>>(
        x, inv_map, lA, lB, lPi, ws, out);
}